// Round 10
// baseline (756.503 us; speedup 1.0000x reference)
//
#include <hip/hip_runtime.h>

#define TOK   65536      // B*N tokens
#define DIMS  256        // D
#define NCODE 2048       // K codebook
#define LOSSOFF 16777216
#define IDXOFF  16777217

typedef _Float16 f16x8 __attribute__((ext_vector_type(8)));
typedef _Float16 f16x4 __attribute__((ext_vector_type(4)));
typedef float    f32x4 __attribute__((ext_vector_type(4)));

__device__ __forceinline__ unsigned long long umin64(unsigned long long a,
                                                     unsigned long long b) {
  return a < b ? a : b;
}

// ---------- K0a: transpose embed [D][K] -> embedT [K][D] fp32 + fp16 hi/lo planes
__global__ void k_prep(const float* __restrict__ embed, float* __restrict__ embedT,
                       _Float16* __restrict__ eTh, _Float16* __restrict__ eTl) {
  __shared__ float t[32][33];
  int tx = threadIdx.x & 31, ty = threadIdx.x >> 5;
  int k0 = blockIdx.x * 32, d0 = blockIdx.y * 32;
#pragma unroll
  for (int i = 0; i < 4; ++i) {
    int d = ty + i * 8;
    t[tx][d] = embed[(size_t)(d0 + d) * NCODE + k0 + tx];
  }
  __syncthreads();
#pragma unroll
  for (int i = 0; i < 4; ++i) {
    int kl = ty + i * 8;
    float v = t[kl][tx];
    size_t o = (size_t)(k0 + kl) * DIMS + d0 + tx;
    embedT[o] = v;
    _Float16 h = (_Float16)v;
    eTh[o] = h;
    eTl[o] = (_Float16)(v - (float)h);
  }
}

// ---------- K0b: e2[k] = sum_d embed[d][k]^2 (fp64 accumulate, deterministic)
__global__ void k_e2(const float* __restrict__ embed, float* __restrict__ e2) {
  int k = blockIdx.x * 256 + threadIdx.x;
  double a = 0.0;
  for (int d = 0; d < DIMS; ++d) {
    float v = embed[(size_t)d * NCODE + k];
    a += (double)v * (double)v;
  }
  e2[k] = (float)a;
}

// ---------- K0c: init loss slot ----------
__global__ void k_init(float* __restrict__ out) { out[LOSSOFF] = 0.0f; }

// ---------- K1: fused split + score GEMM + full argmin, BARRIER-FREE main loop
// Block = 64 tokens x FULL 2048-code codebook. A (hi/lo fp16) staged once into
// 64 KB LDS (on-the-fly fp32->hi/lo split); ONE barrier; then each wave streams
// its 512-code slice from L2 (eT planes = 2 MB, L2-resident/XCD) with zero
// syncthreads. Argmin folds in registers; block-local reduce at the end.
// LDS swizzle: phys 16B-granule P = p ^ (row&7) (write & read sides identical).
#define MM(ah_, al_, bh_, bl_, a_) do { \
  a_ = __builtin_amdgcn_mfma_f32_16x16x32_f16(ah_, bh_, a_, 0, 0, 0); \
  a_ = __builtin_amdgcn_mfma_f32_16x16x32_f16(ah_, bl_, a_, 0, 0, 0); \
  a_ = __builtin_amdgcn_mfma_f32_16x16x32_f16(al_, bh_, a_, 0, 0, 0); } while (0)

__global__ __launch_bounds__(256, 2) void k_score(
    const float* __restrict__ x, const _Float16* __restrict__ eTh,
    const _Float16* __restrict__ eTl, const float* __restrict__ e2,
    float* __restrict__ out, int* __restrict__ idxw) {
  __shared__ __attribute__((aligned(16))) _Float16 Ah[64 * 256];
  __shared__ __attribute__((aligned(16))) _Float16 Al[64 * 256];
  __shared__ unsigned long long W[4][64];

  int tid = threadIdx.x, lane = tid & 63, wid = tid >> 6;
  int t0 = blockIdx.x * 64;
  int col = lane & 15, kg = lane >> 4;
  int cw = wid * 512;                      // wave's codebook-column base

  // ---- stage A once: fp32 -> fp16 hi/lo, swizzled LDS writes (coalesced reads)
#pragma unroll
  for (int j = 0; j < 16; ++j) {
    int row = j * 4 + wid;                 // one row per wave per j; lanes = granules
    f32x4 v = *(const f32x4*)&x[(size_t)(t0 + row) * DIMS + lane * 4];
    f16x4 h, l4;
#pragma unroll
    for (int e = 0; e < 4; ++e) {
      h[e] = (_Float16)v[e];
      l4[e] = (_Float16)(v[e] - (float)h[e]);
    }
    int p = lane >> 1, half = lane & 1;    // 16B LDS granule, 8B half
    int off = row * 256 + ((p ^ (row & 7)) * 8 + half * 4);
    *(f16x4*)&Ah[off] = h;
    *(f16x4*)&Al[off] = l4;
  }
  __syncthreads();                         // the ONLY barrier before the end

  unsigned long long best[4][4];
#pragma unroll
  for (int m = 0; m < 4; ++m)
#pragma unroll
    for (int r = 0; r < 4; ++r) best[m][r] = ~0ull;

#pragma unroll 1
  for (int g = 0; g < 8; ++g) {            // 8 groups of 64 codes per wave
    int cb = cw + g * 64;
    f32x4 acc[4][4] = {};
#pragma unroll
    for (int ks = 0; ks < 8; ++ks) {       // K = 256 in subchunks of 32
      f16x8 bh[4], bl[4];
#pragma unroll
      for (int n = 0; n < 4; ++n) {
        int off = (cb + n * 16 + col) * DIMS + ks * 32 + kg * 8;
        bh[n] = *(const f16x8*)&eTh[off];
        bl[n] = *(const f16x8*)&eTl[off];
      }
      f16x8 ah[4], al[4];
#pragma unroll
      for (int m = 0; m < 4; ++m) {
        int row = m * 16 + col;
        int off = row * 256 + (((ks * 4 + kg) ^ (row & 7)) * 8);
        ah[m] = *(const f16x8*)&Ah[off];
        al[m] = *(const f16x8*)&Al[off];
      }
#pragma unroll
      for (int m = 0; m < 4; ++m)
#pragma unroll
        for (int n = 0; n < 4; ++n)
          MM(ah[m], al[m], bh[n], bl[n], acc[m][n]);
    }
    // fold group into running argmin (registers only)
#pragma unroll
    for (int n = 0; n < 4; ++n) {
      unsigned code = (unsigned)(cb + n * 16 + col);
      float e2v = e2[code];
#pragma unroll
      for (int m = 0; m < 4; ++m)
#pragma unroll
        for (int r = 0; r < 4; ++r) {
          float s = e2v - 2.0f * acc[m][n][r];
          unsigned u = __float_as_uint(s);
          u ^= (u & 0x80000000u) ? 0xFFFFFFFFu : 0x80000000u;
          best[m][r] = umin64(best[m][r], ((unsigned long long)u << 32) | code);
        }
    }
  }

  // reduce over the 16 col-residues (within same kg quarter)
#pragma unroll
  for (int m = 0; m < 4; ++m)
#pragma unroll
    for (int r = 0; r < 4; ++r) {
#pragma unroll
      for (int off = 1; off < 16; off <<= 1)
        best[m][r] = umin64(best[m][r], __shfl_xor(best[m][r], off, 64));
    }
  if (col == 0) {
#pragma unroll
    for (int m = 0; m < 4; ++m)
#pragma unroll
      for (int r = 0; r < 4; ++r)
        W[wid][m * 16 + kg * 4 + r] = best[m][r];
  }
  __syncthreads();
  if (tid < 64) {
    unsigned long long b = umin64(umin64(W[0][tid], W[1][tid]),
                                  umin64(W[2][tid], W[3][tid]));
    int code = (int)(b & 0xFFFFFFFFull);
    idxw[t0 + tid] = code;
    out[IDXOFF + t0 + tid] = (float)code;
  }
}

// ---------- K3: gather codes, STE output, commitment loss ----------
__global__ void k_gather(const float* __restrict__ x, const float* __restrict__ embedT,
                         const int* __restrict__ idxw, float* __restrict__ out) {
  int wid = threadIdx.x >> 6, lane = threadIdx.x & 63;
  int gw = blockIdx.x * 4 + wid;          // 8192 waves, 8 tokens each
  float s = 0.0f;
#pragma unroll
  for (int t = 0; t < 8; ++t) {
    int token = gw * 8 + t;
    int code = idxw[token];               // broadcast load
    f32x4 q  = *(const f32x4*)&embedT[(size_t)code * DIMS + lane * 4];
    f32x4 xv = *(const f32x4*)&x[(size_t)token * DIMS + lane * 4];
    f32x4 d = q - xv;
    *(f32x4*)&out[(size_t)token * DIMS + lane * 4] = xv + d;  // STE: x + (q - x)
    s += d[0] * d[0] + d[1] * d[1] + d[2] * d[2] + d[3] * d[3];
  }
  for (int off = 32; off; off >>= 1) s += __shfl_xor(s, off, 64);
  __shared__ float red[4];
  if (lane == 0) red[wid] = s;
  __syncthreads();
  if (threadIdx.x == 0) {
    float tsum = (red[0] + red[1] + red[2] + red[3]) * (0.25f / 16777216.0f);
    atomicAdd(&out[LOSSOFF], tsum);
  }
}

extern "C" void kernel_launch(void* const* d_in, const int* in_sizes, int n_in,
                              void* d_out, int out_size, void* d_ws, size_t ws_size,
                              hipStream_t stream) {
  const float* x     = (const float*)d_in[0];
  const float* embed = (const float*)d_in[1];
  float* out = (float*)d_out;
  char* w = (char*)d_ws;
  _Float16* eTh    = (_Float16*)w;                               // 1 MB
  _Float16* eTl    = (_Float16*)(w + (1u << 20));                // 1 MB
  float*    embedT = (float*)(w + (2u << 20));                   // 2 MB
  float*    e2     = (float*)(w + (4u << 20));                   // 8 KB
  int*      idxw   = (int*)(w + (4u << 20) + (1u << 15));        // 256 KB

  hipLaunchKernelGGL(k_prep,   dim3(NCODE / 32, DIMS / 32), dim3(256), 0, stream, embed, embedT, eTh, eTl);
  hipLaunchKernelGGL(k_e2,     dim3(NCODE / 256),           dim3(256), 0, stream, embed, e2);
  hipLaunchKernelGGL(k_init,   dim3(1),                     dim3(1),   0, stream, out);
  hipLaunchKernelGGL(k_score,  dim3(TOK / 64),              dim3(256), 0, stream, x, eTh, eTl, e2, out, idxw);
  hipLaunchKernelGGL(k_gather, dim3(TOK / 32 / 8),          dim3(256), 0, stream, x, embedT, idxw, out);
}